// Round 3
// baseline (830.259 us; speedup 1.0000x reference)
//
#include <hip/hip_runtime.h>

#define NN 100000
#define NE 600000
#define NR 6
#define NB 6
#define NKEY (NN * NR)            // 600000 keys: dst*6 + etype
#define NCHUNK ((NKEY + 1023) / 1024)  // 586

__host__ __device__ constexpr int cdiv4(int x) { return (x + 3) / 4; }

// ---------- input padding: nf [NN][26] -> hp [NN][28] ----------
__global__ void pad_feats(const float* __restrict__ nf, float* __restrict__ hp) {
  int idx = blockIdx.x * 256 + threadIdx.x;
  if (idx >= NN * 28) return;
  int n = idx / 28, k = idx - n * 28;
  hp[idx] = (k < 26) ? nf[n * 26 + k] : 0.f;
}

// ---------- CSR build: key = dst*6 + etype ----------
__global__ void hist2(const int* __restrict__ dst, const int* __restrict__ et,
                      int* __restrict__ cnt) {
  int e = blockIdx.x * 256 + threadIdx.x;
  if (e < NE) atomicAdd(&cnt[dst[e] * NR + et[e]], 1);
}

__global__ void scanA(const int* __restrict__ cnt, int* __restrict__ partial) {
  __shared__ int ts[256];
  int t = threadIdx.x;
  int base = blockIdx.x * 1024 + t * 4;
  int s = 0;
#pragma unroll
  for (int i = 0; i < 4; ++i)
    if (base + i < NKEY) s += cnt[base + i];
  ts[t] = s;
  __syncthreads();
  for (int off = 128; off; off >>= 1) {
    if (t < off) ts[t] += ts[t + off];
    __syncthreads();
  }
  if (t == 0) partial[blockIdx.x] = ts[0];
}

__global__ void scanB(int* __restrict__ partial) {
  __shared__ int ts[256];
  int t = threadIdx.x;
  int b = t * 3;
  int v[3], s = 0;
#pragma unroll
  for (int i = 0; i < 3; ++i) {
    v[i] = (b + i < NCHUNK) ? partial[b + i] : 0;
    s += v[i];
  }
  ts[t] = s;
  __syncthreads();
  for (int off = 1; off < 256; off <<= 1) {
    int x = (t >= off) ? ts[t - off] : 0;
    __syncthreads();
    ts[t] += x;
    __syncthreads();
  }
  int run = ts[t] - s;  // exclusive
#pragma unroll
  for (int i = 0; i < 3; ++i) {
    int tmp = v[i];
    if (b + i < NCHUNK) partial[b + i] = run;
    run += tmp;
  }
}

__global__ void scanC(int* __restrict__ cnt, const int* __restrict__ partial,
                      int* __restrict__ indptr, int* __restrict__ cur) {
  __shared__ int ts[256];
  int t = threadIdx.x;
  int base = blockIdx.x * 1024 + t * 4;
  int v[4], s = 0;
#pragma unroll
  for (int i = 0; i < 4; ++i) {
    v[i] = (base + i < NKEY) ? cnt[base + i] : 0;
    s += v[i];
  }
  ts[t] = s;
  __syncthreads();
  for (int off = 1; off < 256; off <<= 1) {
    int x = (t >= off) ? ts[t - off] : 0;
    __syncthreads();
    ts[t] += x;
    __syncthreads();
  }
  int run = partial[blockIdx.x] + ts[t] - s;
#pragma unroll
  for (int i = 0; i < 4; ++i) {
    if (base + i < NKEY) {
      indptr[base + i] = run;
      cur[base + i] = run;
      run += v[i];
    }
  }
  if (blockIdx.x == 0 && t == 0) indptr[NKEY] = NE;
}

__global__ void scatter2(const int* __restrict__ et, const int* __restrict__ src,
                         const int* __restrict__ dst, int* __restrict__ cur,
                         int* __restrict__ sidx) {
  int e = blockIdx.x * 256 + threadIdx.x;
  if (e < NE) {
    int key = dst[e] * NR + et[e];
    int pos = atomicAdd(&cur[key], 1);
    sidx[pos] = src[e];
  }
}

// ---------- weight composition: WT[rel][k4][o] = float4 over k ----------
template <int IN, int OUT>
__global__ void compose_wT(const float* __restrict__ V, const float* __restrict__ C,
                           float4* __restrict__ WT) {
  constexpr int KV = cdiv4(IN);
  int idx = blockIdx.x * 256 + threadIdx.x;
  if (idx >= NR * KV * OUT) return;
  int r = idx / (KV * OUT);
  int rem = idx - r * (KV * OUT);
  int k4 = rem / OUT, o = rem - k4 * OUT;
  float w[4] = {0.f, 0.f, 0.f, 0.f};
#pragma unroll
  for (int kk = 0; kk < 4; ++kk) {
    int k = k4 * 4 + kk;
    if (k < IN) {
      float s = 0.f;
#pragma unroll
      for (int b = 0; b < NB; ++b) s += C[r * NB + b] * V[(b * IN + k) * OUT + o];
      w[kk] = s;
    }
  }
  WT[idx] = make_float4(w[0], w[1], w[2], w[3]);
}

template <int IN, int OUT>
__global__ void transpose_sT(const float* __restrict__ S, float4* __restrict__ WTs) {
  constexpr int KV = cdiv4(IN);
  int idx = blockIdx.x * 256 + threadIdx.x;
  if (idx >= KV * OUT) return;
  int k4 = idx / OUT, o = idx - k4 * OUT;
  float w[4] = {0.f, 0.f, 0.f, 0.f};
#pragma unroll
  for (int kk = 0; kk < 4; ++kk) {
    int k = k4 * 4 + kk;
    if (k < IN) w[kk] = S[k * OUT + o];
  }
  WTs[idx] = make_float4(w[0], w[1], w[2], w[3]);
}

// ---------- fused layer: aggregate-then-transform, W streamed from global ----------
// Block = 512 threads, 64 dst rows. For rel 0..NR (NR = self):
//   build A-tile (segmented gather-sum into LDS), barrier,
//   GEMM: A from LDS, W rows from global (L1/L2-resident), acc in regs, barrier.
// Epilogue: G[row][col] = relu(acc + bias[col]).
template <int IN4, int OUT>
__global__ __launch_bounds__(512, 8) void rgcn_layer(
    const float* __restrict__ h,      // [NN][IN4] padded, pre-relu'd
    const float4* __restrict__ WT,    // [(NR+1)][KV][OUT] float4-over-k
    const float* __restrict__ bias,   // [OUT]
    const int* __restrict__ indptr,   // [NKEY+1]
    const int* __restrict__ sidx,     // [NE]
    float* __restrict__ G) {          // [NN][OUT]
  constexpr int KV = IN4 / 4;
  constexpr int WSV = (KV & 1) ? KV : KV + 1;  // odd float4 stride -> bank spread
  constexpr int CGW = OUT / 4;
  constexpr int NRG = 512 / CGW;
  constexpr int RPT = 64 / NRG;

  __shared__ float4 A4[64 * WSV];
  __shared__ int seg[64 * NR + 1];

  const int tid = threadIdx.x;
  const int row0 = blockIdx.x * 64;
  const float4* __restrict__ h4 = (const float4*)h;

  for (int i = tid; i < 64 * NR + 1; i += 512) {
    int k = row0 * NR + i;
    seg[i] = (k <= NKEY) ? indptr[k] : NE;
  }
  __syncthreads();

  const int colbase = tid % CGW;
  const int rowgrp = tid / CGW;
  float acc[RPT][4];
#pragma unroll
  for (int rr = 0; rr < RPT; ++rr)
#pragma unroll
    for (int j = 0; j < 4; ++j) acc[rr][j] = 0.f;

  for (int rel = 0; rel <= NR; ++rel) {
    // build A tile
    for (int idx = tid; idx < 64 * KV; idx += 512) {
      int j = idx / KV, c = idx - j * KV;
      float4 v = make_float4(0.f, 0.f, 0.f, 0.f);
      int row = row0 + j;
      if (row < NN) {
        if (rel == NR) {
          v = h4[(size_t)row * KV + c];
        } else {
          int beg = seg[j * NR + rel], end = seg[j * NR + rel + 1];
          for (int e = beg; e < end; ++e) {
            float4 t = h4[(size_t)sidx[e] * KV + c];
            v.x += t.x; v.y += t.y; v.z += t.z; v.w += t.w;
          }
        }
      }
      A4[j * WSV + c] = v;
    }
    __syncthreads();

    const float4* __restrict__ Wr = WT + (size_t)rel * KV * OUT;
#pragma unroll 2
    for (int k4 = 0; k4 < KV; ++k4) {
      float4 w[4];
#pragma unroll
      for (int j = 0; j < 4; ++j) w[j] = Wr[k4 * OUT + colbase + j * CGW];
#pragma unroll
      for (int rr = 0; rr < RPT; ++rr) {
        float4 a = A4[(rowgrp * RPT + rr) * WSV + k4];
#pragma unroll
        for (int j = 0; j < 4; ++j)
          acc[rr][j] += a.x * w[j].x + a.y * w[j].y + a.z * w[j].z + a.w * w[j].w;
      }
    }
    __syncthreads();
  }

  // epilogue: bias + relu, single write
#pragma unroll
  for (int rr = 0; rr < RPT; ++rr) {
    int row = row0 + rowgrp * RPT + rr;
    if (row < NN) {
#pragma unroll
      for (int j = 0; j < 4; ++j) {
        int c = colbase + j * CGW;
        G[(size_t)row * OUT + c] = fmaxf(acc[rr][j] + bias[c], 0.f);
      }
    }
  }
}

// ---------- host ----------
static inline char* align_up(char* p, size_t a) {
  return (char*)(((size_t)p + a - 1) & ~(a - 1));
}

extern "C" void kernel_launch(void* const* d_in, const int* in_sizes, int n_in,
                              void* d_out, int out_size, void* d_ws, size_t ws_size,
                              hipStream_t stream) {
  const float* nf = (const float*)d_in[0];
  const int* src  = (const int*)d_in[1];
  const int* dst  = (const int*)d_in[2];
  const int* et   = (const int*)d_in[3];
  const float* V1 = (const float*)d_in[4];
  const float* C1 = (const float*)d_in[5];
  const float* S1 = (const float*)d_in[6];
  const float* b1 = (const float*)d_in[7];
  const float* V2 = (const float*)d_in[8];
  const float* C2 = (const float*)d_in[9];
  const float* S2 = (const float*)d_in[10];
  const float* b2 = (const float*)d_in[11];
  const float* V3 = (const float*)d_in[12];
  const float* C3 = (const float*)d_in[13];
  const float* S3 = (const float*)d_in[14];
  const float* b3 = (const float*)d_in[15];
  float* out = (float*)d_out;

  constexpr int KV1 = cdiv4(26);   // 7
  constexpr int KV2 = cdiv4(64);   // 16
  constexpr int KV3 = cdiv4(128);  // 32

  char* p = (char*)d_ws;
  int* cnt = (int*)p;      p = align_up(p + (size_t)NKEY * 4, 256);         // doubles as cur
  int* indptr = (int*)p;   p = align_up(p + (size_t)(NKEY + 1) * 4, 256);
  int* partial = (int*)p;  p = align_up(p + (size_t)NCHUNK * 4, 256);
  int* sidx = (int*)p;     p = align_up(p + (size_t)NE * 4, 256);
  float* hp = (float*)p;   p = align_up(p + (size_t)NN * 28 * 4, 256);
  float4* W1 = (float4*)p; p = align_up(p + (size_t)(NR + 1) * KV1 * 64 * 16, 256);
  float4* W2 = (float4*)p; p = align_up(p + (size_t)(NR + 1) * KV2 * 128 * 16, 256);
  float4* W3 = (float4*)p; p = align_up(p + (size_t)(NR + 1) * KV3 * 32 * 16, 256);
  float* G1 = (float*)p;   p = align_up(p + (size_t)NN * 64 * 4, 256);
  float* G2 = (float*)p;   p = align_up(p + (size_t)NN * 128 * 4, 256);

  hipMemsetAsync(cnt, 0, (size_t)NKEY * 4, stream);

  const int EB = (NE + 255) / 256;  // 2344
  pad_feats<<<(NN * 28 + 255) / 256, 256, 0, stream>>>(nf, hp);
  hist2<<<EB, 256, 0, stream>>>(dst, et, cnt);
  scanA<<<NCHUNK, 256, 0, stream>>>(cnt, partial);
  scanB<<<1, 256, 0, stream>>>(partial);
  scanC<<<NCHUNK, 256, 0, stream>>>(cnt, partial, indptr, cnt);
  scatter2<<<EB, 256, 0, stream>>>(et, src, dst, cnt, sidx);

  compose_wT<26, 64><<<(NR * KV1 * 64 + 255) / 256, 256, 0, stream>>>(V1, C1, W1);
  compose_wT<64, 128><<<(NR * KV2 * 128 + 255) / 256, 256, 0, stream>>>(V2, C2, W2);
  compose_wT<128, 32><<<(NR * KV3 * 32 + 255) / 256, 256, 0, stream>>>(V3, C3, W3);
  transpose_sT<26, 64><<<(KV1 * 64 + 255) / 256, 256, 0, stream>>>(S1, W1 + (size_t)NR * KV1 * 64);
  transpose_sT<64, 128><<<(KV2 * 128 + 255) / 256, 256, 0, stream>>>(S2, W2 + (size_t)NR * KV2 * 128);
  transpose_sT<128, 32><<<(KV3 * 32 + 255) / 256, 256, 0, stream>>>(S3, W3 + (size_t)NR * KV3 * 32);

  const int NBK = (NN + 63) / 64;  // 1563
  rgcn_layer<28, 64><<<NBK, 512, 0, stream>>>(hp, W1, b1, indptr, sidx, G1);
  rgcn_layer<64, 128><<<NBK, 512, 0, stream>>>(G1, W2, b2, indptr, sidx, G2);
  rgcn_layer<128, 32><<<NBK, 512, 0, stream>>>(G2, W3, b3, indptr, sidx, out);

  (void)in_sizes; (void)n_in; (void)out_size; (void)ws_size;
}

// Round 4
// 247.638 us; speedup vs baseline: 3.3527x; 3.3527x over previous
//
#include <hip/hip_runtime.h>

#define NN 100000
#define NE 600000
#define NR 6
#define NB 6
#define NKEY (NN * NR)            // 600000 keys: dst*6 + etype
#define NCHUNK ((NKEY + 1023) / 1024)  // 586

typedef __attribute__((ext_vector_type(8))) short bfrag;       // 8 bf16 (4 VGPRs)
typedef __attribute__((ext_vector_type(8))) unsigned short uvec8;
typedef __attribute__((ext_vector_type(4))) float accvec;

__device__ __forceinline__ float bf2f(unsigned short u) {
  union { unsigned int i; float f; } v;
  v.i = ((unsigned int)u) << 16;
  return v.f;
}
__device__ __forceinline__ unsigned short f2bf(float f) {
  union { float f; unsigned int i; } v;
  v.f = f;
  return (unsigned short)((v.i + 0x7FFFu + ((v.i >> 16) & 1u)) >> 16);
}

// ---------- input conversion: nf [NN][26] f32 -> hp [NN][32] bf16 ----------
__global__ void pad_feats_bf16(const float* __restrict__ nf, unsigned short* __restrict__ hp) {
  int idx = blockIdx.x * 256 + threadIdx.x;  // one per (n, 8-col chunk)
  if (idx >= NN * 4) return;
  int n = idx >> 2, c = idx & 3;
  uvec8 o;
#pragma unroll
  for (int i = 0; i < 8; ++i) {
    int k = c * 8 + i;
    o[i] = (k < 26) ? f2bf(nf[n * 26 + k]) : (unsigned short)0;
  }
  *(uvec8*)&hp[(size_t)n * 32 + c * 8] = o;
}

// ---------- CSR build: key = dst*6 + etype ----------
__global__ void hist2(const int* __restrict__ dst, const int* __restrict__ et,
                      int* __restrict__ cnt) {
  int e = blockIdx.x * 256 + threadIdx.x;
  if (e < NE) atomicAdd(&cnt[dst[e] * NR + et[e]], 1);
}

__global__ void scanA(const int* __restrict__ cnt, int* __restrict__ partial) {
  __shared__ int ts[256];
  int t = threadIdx.x;
  int base = blockIdx.x * 1024 + t * 4;
  int s = 0;
#pragma unroll
  for (int i = 0; i < 4; ++i)
    if (base + i < NKEY) s += cnt[base + i];
  ts[t] = s;
  __syncthreads();
  for (int off = 128; off; off >>= 1) {
    if (t < off) ts[t] += ts[t + off];
    __syncthreads();
  }
  if (t == 0) partial[blockIdx.x] = ts[0];
}

__global__ void scanB(int* __restrict__ partial) {
  __shared__ int ts[256];
  int t = threadIdx.x;
  int b = t * 3;
  int v[3], s = 0;
#pragma unroll
  for (int i = 0; i < 3; ++i) {
    v[i] = (b + i < NCHUNK) ? partial[b + i] : 0;
    s += v[i];
  }
  ts[t] = s;
  __syncthreads();
  for (int off = 1; off < 256; off <<= 1) {
    int x = (t >= off) ? ts[t - off] : 0;
    __syncthreads();
    ts[t] += x;
    __syncthreads();
  }
  int run = ts[t] - s;  // exclusive
#pragma unroll
  for (int i = 0; i < 3; ++i) {
    int tmp = v[i];
    if (b + i < NCHUNK) partial[b + i] = run;
    run += tmp;
  }
}

__global__ void scanC(int* __restrict__ cnt, const int* __restrict__ partial,
                      int* __restrict__ indptr, int* __restrict__ cur) {
  __shared__ int ts[256];
  int t = threadIdx.x;
  int base = blockIdx.x * 1024 + t * 4;
  int v[4], s = 0;
#pragma unroll
  for (int i = 0; i < 4; ++i) {
    v[i] = (base + i < NKEY) ? cnt[base + i] : 0;
    s += v[i];
  }
  ts[t] = s;
  __syncthreads();
  for (int off = 1; off < 256; off <<= 1) {
    int x = (t >= off) ? ts[t - off] : 0;
    __syncthreads();
    ts[t] += x;
    __syncthreads();
  }
  int run = partial[blockIdx.x] + ts[t] - s;
#pragma unroll
  for (int i = 0; i < 4; ++i) {
    if (base + i < NKEY) {
      indptr[base + i] = run;
      cur[base + i] = run;
      run += v[i];
    }
  }
  if (blockIdx.x == 0 && t == 0) indptr[NKEY] = NE;
}

__global__ void scatter2(const int* __restrict__ et, const int* __restrict__ src,
                         const int* __restrict__ dst, int* __restrict__ cur,
                         int* __restrict__ sidx) {
  int e = blockIdx.x * 256 + threadIdx.x;
  if (e < NE) {
    int key = dst[e] * NR + et[e];
    int pos = atomicAdd(&cur[key], 1);
    sidx[pos] = src[e];
  }
}

// ---------- W composition directly into MFMA B-fragment layout (bf16) ----------
// Wf[((rel*KS + ks)*NT + nt)*64 + lane][i] = W[rel][k][n], k = ks*32 + (lane>>4)*8 + i,
// n = nt*16 + (lane&15). rel==NR -> self weight S. k >= IN -> 0.
template <int IN, int OUT, int KS, int NT>
__global__ void compose_wf(const float* __restrict__ V, const float* __restrict__ C,
                           const float* __restrict__ S, unsigned short* __restrict__ Wf) {
  int idx = blockIdx.x * 256 + threadIdx.x;
  if (idx >= (NR + 1) * KS * NT * 64) return;
  int lane = idx & 63;
  int t = idx >> 6;
  int nt = t % NT; t /= NT;
  int ks = t % KS; int rel = t / KS;
  int n = nt * 16 + (lane & 15);
  int g = lane >> 4;
  uvec8 o;
#pragma unroll
  for (int i = 0; i < 8; ++i) {
    int k = ks * 32 + g * 8 + i;
    float s = 0.f;
    if (k < IN) {
      if (rel < NR) {
#pragma unroll
        for (int b = 0; b < NB; ++b) s += C[rel * NB + b] * V[((size_t)b * IN + k) * OUT + n];
      } else {
        s = S[(size_t)k * OUT + n];
      }
    }
    o[i] = f2bf(s);
  }
  *(uvec8*)&Wf[(size_t)idx * 8] = o;
}

// ---------- fused layer: CSR aggregate (fp32) -> bf16 LDS tile -> MFMA ----------
// Block = 256 threads (4 waves), 64 dst rows; wave wv owns rows wv*16..wv*16+15.
// For rel 0..NR (NR = self): build A-tile, barrier, MFMA-accumulate, barrier.
// Epilogue: relu(acc + bias) -> bf16 G (or f32 d_out for last layer).
template <int K, int OUT, bool LASTF32>
__global__ __launch_bounds__(256, 4) void rgcn_layer_mfma(
    const unsigned short* __restrict__ h,   // [NN][K] bf16 (pre-relu'd)
    const unsigned short* __restrict__ Wf,  // fragment-layout weights
    const float* __restrict__ bias,         // [OUT] f32
    const int* __restrict__ indptr,         // [NKEY+1]
    const int* __restrict__ sidx,           // [NE]
    void* __restrict__ Gout) {
  constexpr int KS = K / 32;
  constexpr int NT = OUT / 16;
  constexpr int KC = K / 8;       // 16B chunks per row
  constexpr int KP = K + 8;       // LDS row stride in bf16 (byte stride 2K+16)

  __shared__ unsigned short Asm[64 * KP];
  __shared__ int seg[64 * NR + 1];

  const int tid = threadIdx.x;
  const int row0 = blockIdx.x * 64;

  for (int i = tid; i < 64 * NR + 1; i += 256) {
    int kk = row0 * NR + i;
    seg[i] = (kk <= NKEY) ? indptr[kk] : NE;
  }

  const int lane = tid & 63;
  const int wv = tid >> 6;
  const int abase = (wv * 16 + (lane & 15)) * KP + (lane >> 4) * 8;

  accvec acc[NT];
#pragma unroll
  for (int nt = 0; nt < NT; ++nt) acc[nt] = 0.f;

  for (int rel = 0; rel <= NR; ++rel) {
    __syncthreads();  // A free (and seg ready on first iter)

    // build A tile (fp32 gather-sum -> bf16)
    for (int idx = tid; idx < 64 * KC; idx += 256) {
      int j = idx / KC, c = idx - (idx / KC) * KC;
      int row = row0 + j;
      uvec8 o = 0;
      if (rel == NR) {
        if (row < NN) o = *(const uvec8*)&h[(size_t)row * K + c * 8];
      } else {
        int beg = seg[j * NR + rel], end = seg[j * NR + rel + 1];
        float s[8] = {0.f, 0.f, 0.f, 0.f, 0.f, 0.f, 0.f, 0.f};
        for (int e = beg; e < end; ++e) {
          uvec8 tv = *(const uvec8*)&h[(size_t)sidx[e] * K + c * 8];
#pragma unroll
          for (int i = 0; i < 8; ++i) s[i] += bf2f(tv[i]);
        }
#pragma unroll
        for (int i = 0; i < 8; ++i) o[i] = f2bf(s[i]);
      }
      *(uvec8*)&Asm[j * KP + c * 8] = o;
    }
    __syncthreads();

    // MFMA accumulate
    const unsigned short* Wr = Wf + (size_t)rel * KS * NT * 512;
#pragma unroll
    for (int ks = 0; ks < KS; ++ks) {
      bfrag af = *(const bfrag*)&Asm[abase + ks * 32];
#pragma unroll
      for (int nt = 0; nt < NT; ++nt) {
        bfrag bf = *(const bfrag*)&Wr[(size_t)((ks * NT + nt) * 64 + lane) * 8];
        acc[nt] = __builtin_amdgcn_mfma_f32_16x16x32_bf16(af, bf, acc[nt], 0, 0, 0);
      }
    }
  }

  // epilogue: bias + relu; D layout col=lane&15, row=(lane>>4)*4+reg
  const int r0 = row0 + wv * 16 + (lane >> 4) * 4;
  const int col0 = lane & 15;
#pragma unroll
  for (int nt = 0; nt < NT; ++nt) {
    int c = nt * 16 + col0;
    float bv = bias[c];
#pragma unroll
    for (int r = 0; r < 4; ++r) {
      int row = r0 + r;
      if (row < NN) {
        float v = fmaxf(acc[nt][r] + bv, 0.f);
        if constexpr (LASTF32)
          ((float*)Gout)[(size_t)row * OUT + c] = v;
        else
          ((unsigned short*)Gout)[(size_t)row * OUT + c] = f2bf(v);
      }
    }
  }
}

// ---------- host ----------
static inline char* align_up(char* p, size_t a) {
  return (char*)(((size_t)p + a - 1) & ~(a - 1));
}

extern "C" void kernel_launch(void* const* d_in, const int* in_sizes, int n_in,
                              void* d_out, int out_size, void* d_ws, size_t ws_size,
                              hipStream_t stream) {
  const float* nf = (const float*)d_in[0];
  const int* src  = (const int*)d_in[1];
  const int* dst  = (const int*)d_in[2];
  const int* et   = (const int*)d_in[3];
  const float* V1 = (const float*)d_in[4];
  const float* C1 = (const float*)d_in[5];
  const float* S1 = (const float*)d_in[6];
  const float* b1 = (const float*)d_in[7];
  const float* V2 = (const float*)d_in[8];
  const float* C2 = (const float*)d_in[9];
  const float* S2 = (const float*)d_in[10];
  const float* b2 = (const float*)d_in[11];
  const float* V3 = (const float*)d_in[12];
  const float* C3 = (const float*)d_in[13];
  const float* S3 = (const float*)d_in[14];
  const float* b3 = (const float*)d_in[15];
  float* out = (float*)d_out;

  // fragment-table element counts (u16): (NR+1)*KS*NT*64*8
  constexpr int WF1 = (NR + 1) * 1 * 4 * 512;  // 14336
  constexpr int WF2 = (NR + 1) * 2 * 8 * 512;  // 57344
  constexpr int WF3 = (NR + 1) * 4 * 2 * 512;  // 28672

  char* p = (char*)d_ws;
  int* cnt = (int*)p;                p = align_up(p + (size_t)NKEY * 4, 256);  // doubles as cur
  int* indptr = (int*)p;             p = align_up(p + (size_t)(NKEY + 1) * 4, 256);
  int* partial = (int*)p;            p = align_up(p + (size_t)NCHUNK * 4, 256);
  int* sidx = (int*)p;               p = align_up(p + (size_t)NE * 4, 256);
  unsigned short* hp = (unsigned short*)p;  p = align_up(p + (size_t)NN * 32 * 2, 256);
  unsigned short* W1 = (unsigned short*)p;  p = align_up(p + (size_t)WF1 * 2, 256);
  unsigned short* W2 = (unsigned short*)p;  p = align_up(p + (size_t)WF2 * 2, 256);
  unsigned short* W3 = (unsigned short*)p;  p = align_up(p + (size_t)WF3 * 2, 256);
  unsigned short* G1 = (unsigned short*)p;  p = align_up(p + (size_t)NN * 64 * 2, 256);
  unsigned short* G2 = (unsigned short*)p;  p = align_up(p + (size_t)NN * 128 * 2, 256);

  hipMemsetAsync(cnt, 0, (size_t)NKEY * 4, stream);

  const int EB = (NE + 255) / 256;  // 2344
  pad_feats_bf16<<<(NN * 4 + 255) / 256, 256, 0, stream>>>(nf, hp);
  hist2<<<EB, 256, 0, stream>>>(dst, et, cnt);
  scanA<<<NCHUNK, 256, 0, stream>>>(cnt, partial);
  scanB<<<1, 256, 0, stream>>>(partial);
  scanC<<<NCHUNK, 256, 0, stream>>>(cnt, partial, indptr, cnt);
  scatter2<<<EB, 256, 0, stream>>>(et, src, dst, cnt, sidx);

  compose_wf<26, 64, 1, 4><<<(WF1 / 8 + 255) / 256, 256, 0, stream>>>(V1, C1, S1, W1);
  compose_wf<64, 128, 2, 8><<<(WF2 / 8 + 255) / 256, 256, 0, stream>>>(V2, C2, S2, W2);
  compose_wf<128, 32, 4, 2><<<(WF3 / 8 + 255) / 256, 256, 0, stream>>>(V3, C3, S3, W3);

  const int NBK = (NN + 63) / 64;  // 1563
  rgcn_layer_mfma<32, 64, false><<<NBK, 256, 0, stream>>>(hp, W1, b1, indptr, sidx, G1);
  rgcn_layer_mfma<64, 128, false><<<NBK, 256, 0, stream>>>(G1, W2, b2, indptr, sidx, G2);
  rgcn_layer_mfma<128, 32, true><<<NBK, 256, 0, stream>>>(G2, W3, b3, indptr, sidx, out);

  (void)in_sizes; (void)n_in; (void)out_size; (void)ws_size;
}

// Round 5
// 228.659 us; speedup vs baseline: 3.6310x; 1.0830x over previous
//
#include <hip/hip_runtime.h>

#define NN 100000
#define NE 600000
#define NR 6
#define NB 6
#define NKEY (NN * NR)            // 600000 keys: dst*6 + etype
#define NCHUNK ((NKEY + 1023) / 1024)  // 586

typedef __attribute__((ext_vector_type(8))) short bfrag;       // 8 bf16 (4 VGPRs)
typedef __attribute__((ext_vector_type(8))) unsigned short uvec8;
typedef __attribute__((ext_vector_type(4))) float accvec;

__device__ __forceinline__ float bf2f(unsigned short u) {
  union { unsigned int i; float f; } v;
  v.i = ((unsigned int)u) << 16;
  return v.f;
}
__device__ __forceinline__ unsigned short f2bf(float f) {
  union { float f; unsigned int i; } v;
  v.f = f;
  return (unsigned short)((v.i + 0x7FFFu + ((v.i >> 16) & 1u)) >> 16);
}

// ---------- input conversion: nf [NN][26] f32 -> hp [NN][32] bf16 ----------
__global__ void pad_feats_bf16(const float* __restrict__ nf, unsigned short* __restrict__ hp) {
  int idx = blockIdx.x * 256 + threadIdx.x;  // one per (n, 8-col chunk)
  if (idx >= NN * 4) return;
  int n = idx >> 2, c = idx & 3;
  uvec8 o;
#pragma unroll
  for (int i = 0; i < 8; ++i) {
    int k = c * 8 + i;
    o[i] = (k < 26) ? f2bf(nf[n * 26 + k]) : (unsigned short)0;
  }
  *(uvec8*)&hp[(size_t)n * 32 + c * 8] = o;
}

// ---------- CSR build: key = dst*6 + etype ----------
__global__ void hist2(const int* __restrict__ dst, const int* __restrict__ et,
                      int* __restrict__ cnt) {
  int e = blockIdx.x * 256 + threadIdx.x;
  if (e < NE) atomicAdd(&cnt[dst[e] * NR + et[e]], 1);
}

__global__ void scanA(const int* __restrict__ cnt, int* __restrict__ partial) {
  __shared__ int ts[256];
  int t = threadIdx.x;
  int base = blockIdx.x * 1024 + t * 4;
  int s = 0;
#pragma unroll
  for (int i = 0; i < 4; ++i)
    if (base + i < NKEY) s += cnt[base + i];
  ts[t] = s;
  __syncthreads();
  for (int off = 128; off; off >>= 1) {
    if (t < off) ts[t] += ts[t + off];
    __syncthreads();
  }
  if (t == 0) partial[blockIdx.x] = ts[0];
}

__global__ void scanB(int* __restrict__ partial) {
  __shared__ int ts[256];
  int t = threadIdx.x;
  int b = t * 3;
  int v[3], s = 0;
#pragma unroll
  for (int i = 0; i < 3; ++i) {
    v[i] = (b + i < NCHUNK) ? partial[b + i] : 0;
    s += v[i];
  }
  ts[t] = s;
  __syncthreads();
  for (int off = 1; off < 256; off <<= 1) {
    int x = (t >= off) ? ts[t - off] : 0;
    __syncthreads();
    ts[t] += x;
    __syncthreads();
  }
  int run = ts[t] - s;  // exclusive
#pragma unroll
  for (int i = 0; i < 3; ++i) {
    int tmp = v[i];
    if (b + i < NCHUNK) partial[b + i] = run;
    run += tmp;
  }
}

__global__ void scanC(int* __restrict__ cnt, const int* __restrict__ partial,
                      int* __restrict__ indptr, int* __restrict__ cur) {
  __shared__ int ts[256];
  int t = threadIdx.x;
  int base = blockIdx.x * 1024 + t * 4;
  int v[4], s = 0;
#pragma unroll
  for (int i = 0; i < 4; ++i) {
    v[i] = (base + i < NKEY) ? cnt[base + i] : 0;
    s += v[i];
  }
  ts[t] = s;
  __syncthreads();
  for (int off = 1; off < 256; off <<= 1) {
    int x = (t >= off) ? ts[t - off] : 0;
    __syncthreads();
    ts[t] += x;
    __syncthreads();
  }
  int run = partial[blockIdx.x] + ts[t] - s;
#pragma unroll
  for (int i = 0; i < 4; ++i) {
    if (base + i < NKEY) {
      indptr[base + i] = run;
      cur[base + i] = run;
      run += v[i];
    }
  }
  if (blockIdx.x == 0 && t == 0) indptr[NKEY] = NE;
}

__global__ void scatter2(const int* __restrict__ et, const int* __restrict__ src,
                         const int* __restrict__ dst, int* __restrict__ cur,
                         int* __restrict__ sidx, int* __restrict__ gidx) {
  int e = blockIdx.x * 256 + threadIdx.x;
  if (e < NE) {
    int r = et[e];
    int s = src[e];
    int key = dst[e] * NR + r;
    int pos = atomicAdd(&cur[key], 1);
    sidx[pos] = s;
    gidx[pos] = r * NN + s;
  }
}

// ---------- W composition directly into MFMA B-fragment layout (bf16) ----------
template <int IN, int OUT, int KS, int NT>
__global__ void compose_wf(const float* __restrict__ V, const float* __restrict__ C,
                           const float* __restrict__ S, unsigned short* __restrict__ Wf) {
  int idx = blockIdx.x * 256 + threadIdx.x;
  if (idx >= (NR + 1) * KS * NT * 64) return;
  int lane = idx & 63;
  int t = idx >> 6;
  int nt = t % NT; t /= NT;
  int ks = t % KS; int rel = t / KS;
  int n = nt * 16 + (lane & 15);
  int g = lane >> 4;
  uvec8 o;
#pragma unroll
  for (int i = 0; i < 8; ++i) {
    int k = ks * 32 + g * 8 + i;
    float s = 0.f;
    if (k < IN) {
      if (rel < NR) {
#pragma unroll
        for (int b = 0; b < NB; ++b) s += C[rel * NB + b] * V[((size_t)b * IN + k) * OUT + n];
      } else {
        s = S[(size_t)k * OUT + n];
      }
    }
    o[i] = f2bf(s);
  }
  *(uvec8*)&Wf[(size_t)idx * 8] = o;
}

// ---------- fused layer (aggregate-first, layers 1 & 2) ----------
template <int K, int OUT, bool LASTF32>
__global__ __launch_bounds__(256, 4) void rgcn_layer_mfma(
    const unsigned short* __restrict__ h,   // [NN][K] bf16 (pre-relu'd)
    const unsigned short* __restrict__ Wf,  // fragment-layout weights
    const float* __restrict__ bias,         // [OUT] f32
    const int* __restrict__ indptr,         // [NKEY+1]
    const int* __restrict__ sidx,           // [NE]
    void* __restrict__ Gout) {
  constexpr int KS = K / 32;
  constexpr int NT = OUT / 16;
  constexpr int KC = K / 8;       // 16B chunks per row
  constexpr int KP = K + 8;       // LDS row stride in bf16

  __shared__ unsigned short Asm[64 * KP];
  __shared__ int seg[64 * NR + 1];

  const int tid = threadIdx.x;
  const int row0 = blockIdx.x * 64;

  for (int i = tid; i < 64 * NR + 1; i += 256) {
    int kk = row0 * NR + i;
    seg[i] = (kk <= NKEY) ? indptr[kk] : NE;
  }

  const int lane = tid & 63;
  const int wv = tid >> 6;
  const int abase = (wv * 16 + (lane & 15)) * KP + (lane >> 4) * 8;

  accvec acc[NT];
#pragma unroll
  for (int nt = 0; nt < NT; ++nt) acc[nt] = 0.f;

  for (int rel = 0; rel <= NR; ++rel) {
    __syncthreads();  // A free (and seg ready on first iter)

    for (int idx = tid; idx < 64 * KC; idx += 256) {
      int j = idx / KC, c = idx - (idx / KC) * KC;
      int row = row0 + j;
      uvec8 o = 0;
      if (rel == NR) {
        if (row < NN) o = *(const uvec8*)&h[(size_t)row * K + c * 8];
      } else {
        int beg = seg[j * NR + rel], end = seg[j * NR + rel + 1];
        float s[8] = {0.f, 0.f, 0.f, 0.f, 0.f, 0.f, 0.f, 0.f};
        for (int e = beg; e < end; ++e) {
          uvec8 tv = *(const uvec8*)&h[(size_t)sidx[e] * K + c * 8];
#pragma unroll
          for (int i = 0; i < 8; ++i) s[i] += bf2f(tv[i]);
        }
#pragma unroll
        for (int i = 0; i < 8; ++i) o[i] = f2bf(s[i]);
      }
      *(uvec8*)&Asm[j * KP + c * 8] = o;
    }
    __syncthreads();

    const unsigned short* Wr = Wf + (size_t)rel * KS * NT * 512;
#pragma unroll
    for (int ks = 0; ks < KS; ++ks) {
      bfrag af = *(const bfrag*)&Asm[abase + ks * 32];
#pragma unroll
      for (int nt = 0; nt < NT; ++nt) {
        bfrag bf = *(const bfrag*)&Wr[(size_t)((ks * NT + nt) * 64 + lane) * 8];
        acc[nt] = __builtin_amdgcn_mfma_f32_16x16x32_bf16(af, bf, acc[nt], 0, 0, 0);
      }
    }
  }

  const int r0 = row0 + wv * 16 + (lane >> 4) * 4;
  const int col0 = lane & 15;
#pragma unroll
  for (int nt = 0; nt < NT; ++nt) {
    int c = nt * 16 + col0;
    float bv = bias[c];
#pragma unroll
    for (int r = 0; r < 4; ++r) {
      int row = r0 + r;
      if (row < NN) {
        float v = fmaxf(acc[nt][r] + bv, 0.f);
        if constexpr (LASTF32)
          ((float*)Gout)[(size_t)row * OUT + c] = v;
        else
          ((unsigned short*)Gout)[(size_t)row * OUT + c] = f2bf(v);
      }
    }
  }
}

// ---------- layer 3 phase A: dense per-relation transform ----------
// Y[rel][n][c] = (h @ W3[rel])[n][c] for rel 0..NR (NR = self via S3). bf16 out.
template <int K, int OUT>
__global__ __launch_bounds__(256, 4) void rgcn_transform(
    const unsigned short* __restrict__ h,   // [NN][K] bf16 (pre-relu'd)
    const unsigned short* __restrict__ Wf,  // fragment layout, NR+1 rels
    unsigned short* __restrict__ Y) {       // [(NR+1)*NN][OUT]
  constexpr int KS = K / 32;
  constexpr int NT = OUT / 16;
  constexpr int KC = K / 8;
  constexpr int KP = K + 8;

  __shared__ unsigned short Asm[64 * KP];
  const int tid = threadIdx.x;
  const int row0 = blockIdx.x * 64;

  for (int idx = tid; idx < 64 * KC; idx += 256) {
    int j = idx / KC, c = idx - (idx / KC) * KC;
    int row = row0 + j;
    uvec8 o = 0;
    if (row < NN) o = *(const uvec8*)&h[(size_t)row * K + c * 8];
    *(uvec8*)&Asm[j * KP + c * 8] = o;
  }
  __syncthreads();

  const int lane = tid & 63;
  const int wv = tid >> 6;
  const int abase = (wv * 16 + (lane & 15)) * KP + (lane >> 4) * 8;

  bfrag af[KS];
#pragma unroll
  for (int ks = 0; ks < KS; ++ks) af[ks] = *(const bfrag*)&Asm[abase + ks * 32];

  const int r0 = row0 + wv * 16 + (lane >> 4) * 4;
  const int col0 = lane & 15;

  for (int rel = 0; rel <= NR; ++rel) {
    accvec acc[NT];
#pragma unroll
    for (int nt = 0; nt < NT; ++nt) acc[nt] = 0.f;
    const unsigned short* Wr = Wf + (size_t)rel * KS * NT * 512;
#pragma unroll
    for (int ks = 0; ks < KS; ++ks) {
#pragma unroll
      for (int nt = 0; nt < NT; ++nt) {
        bfrag bf = *(const bfrag*)&Wr[(size_t)((ks * NT + nt) * 64 + lane) * 8];
        acc[nt] = __builtin_amdgcn_mfma_f32_16x16x32_bf16(af[ks], bf, acc[nt], 0, 0, 0);
      }
    }
#pragma unroll
    for (int nt = 0; nt < NT; ++nt) {
      int c = nt * 16 + col0;
#pragma unroll
      for (int r = 0; r < 4; ++r) {
        int row = r0 + r;
        if (row < NN)
          Y[((size_t)rel * NN + row) * OUT + c] = f2bf(acc[nt][r]);
      }
    }
  }
}

// ---------- layer 3 phase B: flat segment-sum over all relations ----------
// out[d][c] = relu( sum_{e in dst(d)} Y[gidx[e]][c] + Y[NR*NN+d][c] + bias[c] )
__global__ __launch_bounds__(256, 8) void rgcn_agg3(
    const unsigned short* __restrict__ Y,   // [(NR+1)*NN][32]
    const int* __restrict__ indptr,         // [NKEY+1]
    const int* __restrict__ gidx,           // [NE] = et*NN + src, sorted by dst
    const float* __restrict__ bias,         // [32]
    float* __restrict__ out) {              // [NN][32] f32
  int t = blockIdx.x * 256 + threadIdx.x;
  int row = t >> 2;
  if (row >= NN) return;
  int c = (t & 3) * 8;

  int beg = indptr[row * NR];
  int end = indptr[row * NR + NR];

  float s[8] = {0.f, 0.f, 0.f, 0.f, 0.f, 0.f, 0.f, 0.f};
  int e = beg;
  for (; e + 1 < end; e += 2) {
    int g0 = gidx[e], g1 = gidx[e + 1];
    uvec8 v0 = *(const uvec8*)&Y[(size_t)g0 * 32 + c];
    uvec8 v1 = *(const uvec8*)&Y[(size_t)g1 * 32 + c];
#pragma unroll
    for (int i = 0; i < 8; ++i) s[i] += bf2f(v0[i]) + bf2f(v1[i]);
  }
  if (e < end) {
    int g = gidx[e];
    uvec8 v = *(const uvec8*)&Y[(size_t)g * 32 + c];
#pragma unroll
    for (int i = 0; i < 8; ++i) s[i] += bf2f(v[i]);
  }
  // self
  uvec8 vs = *(const uvec8*)&Y[((size_t)NR * NN + row) * 32 + c];
#pragma unroll
  for (int i = 0; i < 8; ++i) s[i] += bf2f(vs[i]);

  float4 o0, o1;
  o0.x = fmaxf(s[0] + bias[c + 0], 0.f);
  o0.y = fmaxf(s[1] + bias[c + 1], 0.f);
  o0.z = fmaxf(s[2] + bias[c + 2], 0.f);
  o0.w = fmaxf(s[3] + bias[c + 3], 0.f);
  o1.x = fmaxf(s[4] + bias[c + 4], 0.f);
  o1.y = fmaxf(s[5] + bias[c + 5], 0.f);
  o1.z = fmaxf(s[6] + bias[c + 6], 0.f);
  o1.w = fmaxf(s[7] + bias[c + 7], 0.f);
  *(float4*)&out[(size_t)row * 32 + c] = o0;
  *(float4*)&out[(size_t)row * 32 + c + 4] = o1;
}

// ---------- host ----------
static inline char* align_up(char* p, size_t a) {
  return (char*)(((size_t)p + a - 1) & ~(a - 1));
}

extern "C" void kernel_launch(void* const* d_in, const int* in_sizes, int n_in,
                              void* d_out, int out_size, void* d_ws, size_t ws_size,
                              hipStream_t stream) {
  const float* nf = (const float*)d_in[0];
  const int* src  = (const int*)d_in[1];
  const int* dst  = (const int*)d_in[2];
  const int* et   = (const int*)d_in[3];
  const float* V1 = (const float*)d_in[4];
  const float* C1 = (const float*)d_in[5];
  const float* S1 = (const float*)d_in[6];
  const float* b1 = (const float*)d_in[7];
  const float* V2 = (const float*)d_in[8];
  const float* C2 = (const float*)d_in[9];
  const float* S2 = (const float*)d_in[10];
  const float* b2 = (const float*)d_in[11];
  const float* V3 = (const float*)d_in[12];
  const float* C3 = (const float*)d_in[13];
  const float* S3 = (const float*)d_in[14];
  const float* b3 = (const float*)d_in[15];
  float* out = (float*)d_out;

  // fragment-table element counts (u16): (NR+1)*KS*NT*64*8
  constexpr int WF1 = (NR + 1) * 1 * 4 * 512;  // 14336
  constexpr int WF2 = (NR + 1) * 2 * 8 * 512;  // 57344
  constexpr int WF3 = (NR + 1) * 4 * 2 * 512;  // 28672

  char* p = (char*)d_ws;
  int* cnt = (int*)p;                p = align_up(p + (size_t)NKEY * 4, 256);  // doubles as cur
  int* indptr = (int*)p;             p = align_up(p + (size_t)(NKEY + 1) * 4, 256);
  int* partial = (int*)p;            p = align_up(p + (size_t)NCHUNK * 4, 256);
  int* sidx = (int*)p;               p = align_up(p + (size_t)NE * 4, 256);
  int* gidx = (int*)p;               p = align_up(p + (size_t)NE * 4, 256);
  unsigned short* hp = (unsigned short*)p;  p = align_up(p + (size_t)NN * 32 * 2, 256);
  unsigned short* W1 = (unsigned short*)p;  p = align_up(p + (size_t)WF1 * 2, 256);
  unsigned short* W2 = (unsigned short*)p;  p = align_up(p + (size_t)WF2 * 2, 256);
  unsigned short* W3 = (unsigned short*)p;  p = align_up(p + (size_t)WF3 * 2, 256);
  unsigned short* G1 = (unsigned short*)p;  p = align_up(p + (size_t)NN * 64 * 2, 256);
  unsigned short* G2 = (unsigned short*)p;  p = align_up(p + (size_t)NN * 128 * 2, 256);
  unsigned short* Y3 = (unsigned short*)p;  p = align_up(p + (size_t)(NR + 1) * NN * 32 * 2, 256);

  hipMemsetAsync(cnt, 0, (size_t)NKEY * 4, stream);

  const int EB = (NE + 255) / 256;  // 2344
  pad_feats_bf16<<<(NN * 4 + 255) / 256, 256, 0, stream>>>(nf, hp);
  hist2<<<EB, 256, 0, stream>>>(dst, et, cnt);
  scanA<<<NCHUNK, 256, 0, stream>>>(cnt, partial);
  scanB<<<1, 256, 0, stream>>>(partial);
  scanC<<<NCHUNK, 256, 0, stream>>>(cnt, partial, indptr, cnt);
  scatter2<<<EB, 256, 0, stream>>>(et, src, dst, cnt, sidx, gidx);

  compose_wf<26, 64, 1, 4><<<(WF1 / 8 + 255) / 256, 256, 0, stream>>>(V1, C1, S1, W1);
  compose_wf<64, 128, 2, 8><<<(WF2 / 8 + 255) / 256, 256, 0, stream>>>(V2, C2, S2, W2);
  compose_wf<128, 32, 4, 2><<<(WF3 / 8 + 255) / 256, 256, 0, stream>>>(V3, C3, S3, W3);

  const int NBK = (NN + 63) / 64;  // 1563
  rgcn_layer_mfma<32, 64, false><<<NBK, 256, 0, stream>>>(hp, W1, b1, indptr, sidx, G1);
  rgcn_layer_mfma<64, 128, false><<<NBK, 256, 0, stream>>>(G1, W2, b2, indptr, sidx, G2);

  // layer 3: transform-first (IN=128 > OUT=32)
  rgcn_transform<128, 32><<<NBK, 256, 0, stream>>>(G2, W3, Y3);
  rgcn_agg3<<<(NN * 4 + 255) / 256, 256, 0, stream>>>(Y3, indptr, gidx, b3, out);

  (void)in_sizes; (void)n_in; (void)out_size; (void)ws_size;
}